// Round 12
// baseline (136.422 us; speedup 1.0000x reference)
//
#include <hip/hip_runtime.h>
#include <stdint.h>

// GCN: h = relu( D^-1/2 (A+I) D^-1/2 (x@W1) + b1 ); z = h@W2 + b2
// out = [h (N*3) | z (N*7)] float32.
//
// Round-12: round-11's k_pre (80us) is bin-role straggler-bound: 256 blocks x
// 3 serial phases of LDS-atomic chains. Fix: nbin=768 (per-block work /3,
// dense runs still ~43 B write-once), merge cnt2+dinv2 into k_deg (1 block per
// bucket, LDS histogram + in-place g4 scale), 4-deep ILP gather loops.
//   k_pre : [bin role: count/atomic-reserve/scatter] + [xw1 feature-split role]
//   k_deg : per-bucket degree histogram + g4 = {h*dinv, dinv} (merged)
//   k_msg2: message accumulate over valid range (SPLIT=8, 4-ILP loop) -> psum
//   k_fin : reduce + fused epilogue
// Norm factored: agg[d] = dinv[d]*( sum_{s->d} h[s]dinv[s] + h[d]dinv[d] ).

#define BSHIFT 8
#define BNODES 256
#define BPAD 392      // padded per-block bucket arrays
#define CAPM 16384    // record slots per bucket (mean 8184, sigma 90 -> +91s)
#define SPLITC 8      // msg2 slices per bucket
#define NBX 1024      // xw1-role blocks in k_pre

// block-wide int64-vs-int32 ballot: int64 LE => odd 32-bit words of first 256
// entries are all zero (ids < 2^17). Call from ALL threads before divergence.
__device__ __forceinline__ bool ei_is64(const unsigned* __restrict__ ei) {
    const int t = threadIdx.x;
    const int nz = (t < 256) && (ei[2 * t + 1] != 0u);
    return __syncthreads_or(nz) == 0;
}

// ---------- fused: [count/reserve/scatter bin role | x@W1 role] ----------
__global__ __launch_bounds__(512) void k_pre(const float* __restrict__ x,
                                             const float* __restrict__ W1,
                                             float4* __restrict__ part4,
                                             const unsigned* __restrict__ ei,
                                             unsigned* __restrict__ gtotal,
                                             unsigned* __restrict__ records,
                                             int E, int B, int CH, int nbin, int N) {
    const bool is64 = ei_is64(ei);
    if ((int)blockIdx.x < nbin) {
        __shared__ unsigned cnt[BPAD], base[BPAD], cur[BPAD];
        for (int i = threadIdx.x; i < BPAD; i += 512) { cnt[i] = 0u; cur[i] = 0u; }
        __syncthreads();
        const int e0 = blockIdx.x * CH;
        const int e1 = min(E, e0 + CH);
        // ---- phase 1: LDS histogram of dst buckets ----
        if (is64) {
            const uint4* dp = (const uint4*)(ei + 2 * (size_t)E + 2 * e0);
            const int n2 = (e1 - e0) >> 1;  // uint4 = 2 edges (lo words at .x/.z)
            for (int q = threadIdx.x; q < n2; q += 512) {
                const uint4 v = dp[q];
                atomicAdd(&cnt[v.x >> BSHIFT], 1u);
                atomicAdd(&cnt[v.z >> BSHIFT], 1u);
            }
            for (int e = e0 + 2 * n2 + threadIdx.x; e < e1; e += 512)
                atomicAdd(&cnt[ei[2 * (size_t)E + 2 * e] >> BSHIFT], 1u);
        } else {
            const uint4* dp = (const uint4*)(ei + (size_t)E + e0);
            const int n4 = (e1 - e0) >> 2;
            for (int q = threadIdx.x; q < n4; q += 512) {
                const uint4 v = dp[q];
                atomicAdd(&cnt[v.x >> BSHIFT], 1u);
                atomicAdd(&cnt[v.y >> BSHIFT], 1u);
                atomicAdd(&cnt[v.z >> BSHIFT], 1u);
                atomicAdd(&cnt[v.w >> BSHIFT], 1u);
            }
            for (int e = e0 + 4 * n4 + threadIdx.x; e < e1; e += 512)
                atomicAdd(&cnt[ei[(size_t)E + e] >> BSHIFT], 1u);
        }
        __syncthreads();
        // ---- phase 2: atomic reserve (order-free disjoint dense runs) ----
        for (int i = threadIdx.x; i < B; i += 512)
            base[i] = cnt[i] ? atomicAdd(&gtotal[i], cnt[i]) : 0u;
        __syncthreads();
        // ---- phase 3: scatter (chunk re-read is L2/L3-hot) ----
        auto emit = [&](unsigned s, unsigned d) {
            const unsigned bb  = d >> BSHIFT;
            const unsigned idx = atomicAdd(&cur[bb], 1u);
            const unsigned pos = base[bb] + idx;
            if (pos < (unsigned)CAPM)  // safety clamp; never hit at +91 sigma
                records[(size_t)bb * CAPM + pos] = (s << BSHIFT) | (d & (BNODES - 1));
        };
        const int nq = (e1 - e0) >> 2;
        if (is64) {
            const unsigned long long* e64 = (const unsigned long long*)ei;
            const ulonglong2* sp = (const ulonglong2*)(e64 + e0);
            const ulonglong2* dp = (const ulonglong2*)(e64 + (size_t)E + e0);
            for (int q = threadIdx.x; q < nq; q += 512) {
                const ulonglong2 sa = sp[2 * q], sb = sp[2 * q + 1];
                const ulonglong2 da = dp[2 * q], db = dp[2 * q + 1];
                emit((unsigned)sa.x, (unsigned)da.x);
                emit((unsigned)sa.y, (unsigned)da.y);
                emit((unsigned)sb.x, (unsigned)db.x);
                emit((unsigned)sb.y, (unsigned)db.y);
            }
            for (int e = e0 + 4 * nq + threadIdx.x; e < e1; e += 512)
                emit((unsigned)e64[e], (unsigned)e64[(size_t)E + e]);
        } else {
            const uint4* sp = (const uint4*)(ei + e0);
            const uint4* dp = (const uint4*)(ei + (size_t)E + e0);
            for (int q = threadIdx.x; q < nq; q += 512) {
                const uint4 s4 = sp[q], d4 = dp[q];
                emit(s4.x, d4.x);
                emit(s4.y, d4.y);
                emit(s4.z, d4.z);
                emit(s4.w, d4.w);
            }
            for (int e = e0 + 4 * nq + threadIdx.x; e < e1; e += 512)
                emit(ei[e], ei[(size_t)E + e]);
        }
    } else {
        // ---- xw1 role: wave = 4 nodes x 64-feature chunk (f = wave&3) ----
        const int bx     = blockIdx.x - nbin;
        const int gtid   = bx * 512 + threadIdx.x;
        const int nwaves = (((int)gridDim.x - nbin) * 512) >> 6;
        const int wave   = gtid >> 6;
        const int lane   = threadIdx.x & 63;
        const int fg     = lane & 15;
        const int m      = lane >> 4;
        const int f      = wave & 3;
        const int wq     = wave >> 2;
        const int wstep  = nwaves >> 2;
        float w[4][3];
#pragma unroll
        for (int j = 0; j < 4; ++j)
#pragma unroll
            for (int c = 0; c < 3; ++c)
                w[j][c] = W1[(f * 64 + fg * 4 + j) * 3 + c];
        const int nq = (N + 3) >> 2;
        for (int q = wq; q < nq; q += 4 * wstep) {
            int nd[4]; bool ok[4]; float4 v[4];
#pragma unroll
            for (int u = 0; u < 4; ++u) {
                const int qu = q + u * wstep;
                nd[u] = qu * 4 + m;
                ok[u] = (qu < nq) && (nd[u] < N);
                v[u]  = ok[u] ? *reinterpret_cast<const float4*>(
                                    x + (size_t)nd[u] * 256 + f * 64 + fg * 4)
                              : make_float4(0.f, 0.f, 0.f, 0.f);
            }
#pragma unroll
            for (int u = 0; u < 4; ++u) {
                float s0 = v[u].x * w[0][0] + v[u].y * w[1][0] + v[u].z * w[2][0] + v[u].w * w[3][0];
                float s1 = v[u].x * w[0][1] + v[u].y * w[1][1] + v[u].z * w[2][1] + v[u].w * w[3][1];
                float s2 = v[u].x * w[0][2] + v[u].y * w[1][2] + v[u].z * w[2][2] + v[u].w * w[3][2];
#pragma unroll
                for (int off = 8; off >= 1; off >>= 1) {
                    s0 += __shfl_xor(s0, off, 64);
                    s1 += __shfl_xor(s1, off, 64);
                    s2 += __shfl_xor(s2, off, 64);
                }
                if (ok[u] && fg == 0)
                    part4[(size_t)f * N + nd[u]] = make_float4(s0, s1, s2, 0.f);
            }
        }
    }
}

// ---------- merged: per-bucket degree histogram + g4 = {h*dinv, dinv} ----------
__global__ __launch_bounds__(256) void k_deg(const unsigned* __restrict__ records,
                                             const unsigned* __restrict__ gtotal,
                                             const float4* __restrict__ part4,
                                             float* __restrict__ g4, int N) {
    __shared__ unsigned cnt[BNODES];
    const int b = blockIdx.x;
    cnt[threadIdx.x] = 0u;
    __syncthreads();
    int n = (int)gtotal[b]; if (n > CAPM) n = CAPM;
    const unsigned* rec = records + (size_t)b * CAPM;
    for (int i = threadIdx.x; i < n; i += 1024) {  // 4-deep ILP, guarded
        const bool v1 = (i + 256) < n, v2 = (i + 512) < n, v3 = (i + 768) < n;
        const unsigned r0 = rec[i];
        const unsigned r1 = v1 ? rec[i + 256] : 0u;
        const unsigned r2 = v2 ? rec[i + 512] : 0u;
        const unsigned r3 = v3 ? rec[i + 768] : 0u;
        atomicAdd(&cnt[r0 & (BNODES - 1)], 1u);
        if (v1) atomicAdd(&cnt[r1 & (BNODES - 1)], 1u);
        if (v2) atomicAdd(&cnt[r2 & (BNODES - 1)], 1u);
        if (v3) atomicAdd(&cnt[r3 & (BNODES - 1)], 1u);
    }
    __syncthreads();
    const int node = (b << BSHIFT) + threadIdx.x;
    if (node < N) {
        const float4 p0 = part4[node];
        const float4 p1 = part4[(size_t)N + node];
        const float4 p2 = part4[(size_t)2 * N + node];
        const float4 p3 = part4[(size_t)3 * N + node];
        const float hx = p0.x + p1.x + p2.x + p3.x;
        const float hy = p0.y + p1.y + p2.y + p3.y;
        const float hz = p0.z + p1.z + p2.z + p3.z;
        const float r = rsqrtf(1.0f + (float)cnt[threadIdx.x]);  // +1 self-loop
        reinterpret_cast<float4*>(g4)[node] = make_float4(hx * r, hy * r, hz * r, r);
    }
}

// ---------- message accumulate: uniform-bound 4-ILP loop, SPLIT=8 ----------
__global__ __launch_bounds__(256) void k_msg2(const unsigned* __restrict__ records,
                                              const unsigned* __restrict__ total,
                                              const float* __restrict__ g4,
                                              float* __restrict__ psum) {
    __shared__ float acc[BNODES * 3];
    const int b  = blockIdx.x >> 3;
    const int sl = blockIdx.x & 7;
    for (int i = threadIdx.x; i < BNODES * 3; i += 256) acc[i] = 0.f;
    __syncthreads();
    int n = (int)total[b]; if (n > CAPM) n = CAPM;
    const int chunk = (n + SPLITC - 1) / SPLITC;
    const int lo = sl * chunk;
    const int hi = min(n, lo + chunk);
    const unsigned* rec = records + (size_t)b * CAPM;
    const float4* g4v = reinterpret_cast<const float4*>(g4);
    for (int i = lo + threadIdx.x; i < hi; i += 1024) {  // 4 gathers in flight
        const bool v1 = (i + 256) < hi, v2 = (i + 512) < hi, v3 = (i + 768) < hi;
        const unsigned r0 = rec[i];
        const unsigned r1 = v1 ? rec[i + 256] : 0u;
        const unsigned r2 = v2 ? rec[i + 512] : 0u;
        const unsigned r3 = v3 ? rec[i + 768] : 0u;
        const float4 g0 = g4v[r0 >> BSHIFT];
        const float4 g1 = g4v[r1 >> BSHIFT];
        const float4 g2 = g4v[r2 >> BSHIFT];
        const float4 g3 = g4v[r3 >> BSHIFT];
        const unsigned l0 = (r0 & (BNODES - 1)) * 3;
        atomicAdd(&acc[l0 + 0], g0.x); atomicAdd(&acc[l0 + 1], g0.y); atomicAdd(&acc[l0 + 2], g0.z);
        if (v1) {
            const unsigned l1 = (r1 & (BNODES - 1)) * 3;
            atomicAdd(&acc[l1 + 0], g1.x); atomicAdd(&acc[l1 + 1], g1.y); atomicAdd(&acc[l1 + 2], g1.z);
        }
        if (v2) {
            const unsigned l2 = (r2 & (BNODES - 1)) * 3;
            atomicAdd(&acc[l2 + 0], g2.x); atomicAdd(&acc[l2 + 1], g2.y); atomicAdd(&acc[l2 + 2], g2.z);
        }
        if (v3) {
            const unsigned l3 = (r3 & (BNODES - 1)) * 3;
            atomicAdd(&acc[l3 + 0], g3.x); atomicAdd(&acc[l3 + 1], g3.y); atomicAdd(&acc[l3 + 2], g3.z);
        }
    }
    __syncthreads();
    const size_t base = ((size_t)blockIdx.x * 3) << BSHIFT;  // [slice][c][256]
    psum[base +   0 + threadIdx.x] = acc[threadIdx.x * 3 + 0];
    psum[base + 256 + threadIdx.x] = acc[threadIdx.x * 3 + 1];
    psum[base + 512 + threadIdx.x] = acc[threadIdx.x * 3 + 2];
}

// ---------- reduce msg partials + fused epilogue ----------
__global__ __launch_bounds__(256) void k_fin(const float* __restrict__ psum,
                                             const float* __restrict__ g4,
                                             const float* __restrict__ b1,
                                             const float* __restrict__ W2,
                                             const float* __restrict__ b2,
                                             float* __restrict__ out, int N) {
    const int i = blockIdx.x * 256 + threadIdx.x;
    if (i >= N) return;
    const int b = i >> BSHIFT, t = i & (BNODES - 1);
    float a0 = 0.f, a1 = 0.f, a2 = 0.f;
#pragma unroll
    for (int s = 0; s < SPLITC; ++s) {
        const size_t base = (((size_t)b * SPLITC + s) * 3) << BSHIFT;
        a0 += psum[base + t];
        a1 += psum[base + 256 + t];
        a2 += psum[base + 512 + t];
    }
    const float4 g = reinterpret_cast<const float4*>(g4)[i];
    const float  r = g.w;
    const float h0 = fmaxf(r * (a0 + g.x) + b1[0], 0.f);
    const float h1 = fmaxf(r * (a1 + g.y) + b1[1], 0.f);
    const float h2 = fmaxf(r * (a2 + g.z) + b1[2], 0.f);
    out[3 * (size_t)i + 0] = h0;
    out[3 * (size_t)i + 1] = h1;
    out[3 * (size_t)i + 2] = h2;
    float* z = out + (size_t)3 * N;
#pragma unroll
    for (int c = 0; c < 7; ++c)
        z[7 * (size_t)i + c] = h0 * W2[c] + h1 * W2[7 + c] + h2 * W2[14 + c] + b2[c];
}

// ================= fallback (atomic path; only if ws too small) =============
__global__ __launch_bounds__(256) void k_xw1_fb(const float* __restrict__ x,
                                                const float* __restrict__ W1,
                                                float* __restrict__ g4,
                                                unsigned* __restrict__ zptr,
                                                int nzero, int N) {
    const int gtid = blockIdx.x * 256 + threadIdx.x;
    const int nthread = gridDim.x * 256;
    for (int i = gtid; i < nzero; i += nthread) zptr[i] = 0u;
    const int lane = threadIdx.x & 63;
    float w[4][3];
#pragma unroll
    for (int k = 0; k < 4; ++k)
#pragma unroll
        for (int c = 0; c < 3; ++c) w[k][c] = W1[(lane * 4 + k) * 3 + c];
    const int wave = gtid >> 6, nwaves = nthread >> 6;
    for (int node = wave; node < N; node += nwaves) {
        const float4 v = *reinterpret_cast<const float4*>(x + (size_t)node * 256 + lane * 4);
        float s0 = v.x * w[0][0] + v.y * w[1][0] + v.z * w[2][0] + v.w * w[3][0];
        float s1 = v.x * w[0][1] + v.y * w[1][1] + v.z * w[2][1] + v.w * w[3][1];
        float s2 = v.x * w[0][2] + v.y * w[1][2] + v.z * w[2][2] + v.w * w[3][2];
#pragma unroll
        for (int off = 32; off > 0; off >>= 1) {
            s0 += __shfl_xor(s0, off, 64);
            s1 += __shfl_xor(s1, off, 64);
            s2 += __shfl_xor(s2, off, 64);
        }
        if (lane == 0)
            reinterpret_cast<float4*>(g4)[node] = make_float4(s0, s1, s2, 0.f);
    }
}
__global__ __launch_bounds__(256) void k_deg_fb(const unsigned* __restrict__ ei,
                                                float* __restrict__ deg, int E) {
    const bool is64 = ei_is64(ei);
    const int e = blockIdx.x * 256 + threadIdx.x;
    if (e >= E) return;
    const unsigned d = is64 ? (unsigned)((const unsigned long long*)ei)[(size_t)E + e]
                            : ei[(size_t)E + e];
    atomicAdd(&deg[d], 1.0f);
}
__global__ __launch_bounds__(256) void k_dinv_fb(const float* __restrict__ deg,
                                                 float* __restrict__ g4, int N) {
    const int i = blockIdx.x * 256 + threadIdx.x;
    if (i >= N) return;
    const float r = rsqrtf(1.0f + deg[i]);
    const float4 h = reinterpret_cast<const float4*>(g4)[i];
    reinterpret_cast<float4*>(g4)[i] = make_float4(h.x * r, h.y * r, h.z * r, r);
}
__global__ __launch_bounds__(256) void k_edge_fb(const unsigned* __restrict__ ei,
                                                 const float* __restrict__ g4,
                                                 float* __restrict__ u4, int E) {
    const bool is64 = ei_is64(ei);
    const int e = blockIdx.x * 256 + threadIdx.x;
    if (e >= E) return;
    unsigned s, d;
    if (is64) {
        const unsigned long long* q = (const unsigned long long*)ei;
        s = (unsigned)q[e]; d = (unsigned)q[(size_t)E + e];
    } else {
        s = ei[e]; d = ei[(size_t)E + e];
    }
    const float4 g = reinterpret_cast<const float4*>(g4)[s];
    atomicAdd(&u4[4 * (size_t)d + 0], g.x);
    atomicAdd(&u4[4 * (size_t)d + 1], g.y);
    atomicAdd(&u4[4 * (size_t)d + 2], g.z);
}
__global__ __launch_bounds__(256) void k_final_fb(const float* __restrict__ u4,
                                                  const float* __restrict__ g4,
                                                  const float* __restrict__ b1,
                                                  const float* __restrict__ W2,
                                                  const float* __restrict__ b2,
                                                  float* __restrict__ out, int N) {
    const int i = blockIdx.x * 256 + threadIdx.x;
    if (i >= N) return;
    const float4 g = reinterpret_cast<const float4*>(g4)[i];
    const float4 u = reinterpret_cast<const float4*>(u4)[i];
    const float  r = g.w;
    const float h0 = fmaxf(r * (u.x + g.x) + b1[0], 0.f);
    const float h1 = fmaxf(r * (u.y + g.y) + b1[1], 0.f);
    const float h2 = fmaxf(r * (u.z + g.z) + b1[2], 0.f);
    out[3 * (size_t)i + 0] = h0;
    out[3 * (size_t)i + 1] = h1;
    out[3 * (size_t)i + 2] = h2;
    float* z = out + (size_t)3 * N;
#pragma unroll
    for (int c = 0; c < 7; ++c)
        z[7 * (size_t)i + c] = h0 * W2[c] + h1 * W2[7 + c] + h2 * W2[14 + c] + b2[c];
}

extern "C" void kernel_launch(void* const* d_in, const int* in_sizes, int n_in,
                              void* d_out, int out_size, void* d_ws, size_t ws_size,
                              hipStream_t stream) {
    const float*    x   = (const float*)d_in[0];
    const unsigned* ei  = (const unsigned*)d_in[1];
    const float*    W1  = (const float*)d_in[2];
    const float*    b1  = (const float*)d_in[3];
    const float*    W2  = (const float*)d_in[4];
    const float*    b2  = (const float*)d_in[5];
    float*          out = (float*)d_out;

    const int N = in_sizes[0] / 256;          // 100000
    const int E = in_sizes[1] / 2;            // 3200000
    const int B = (N + BNODES - 1) >> BSHIFT; // 391

    // bin geometry: ~768 blocks (runs ~10.7 records = 43 B, dense write-once)
    const int CH   = ((E + 767) / 768 + 3) & ~3;
    const int nbin = (E + CH - 1) / CH;       // <= 768

    // ---- workspace layout ----
    char* ws = (char*)d_ws;
    size_t off = 256;
    float*    g4      = (float*)(ws + off);                // 4N {h*dinv, dinv}
    off = (off + 16ull * N + 255) & ~(size_t)255;
    float4*   part4   = (float4*)(ws + off);               // 4 x N xw1 partials
    off = (off + 64ull * N + 255) & ~(size_t)255;
    unsigned* gtotal  = (unsigned*)(ws + off);             // B (memset to 0)
    off = (off + 4ull * B + 255) & ~(size_t)255;
    float*    psum    = (float*)(ws + off);                // B*SPLITC*768 f32
    off = (off + 4ull * B * SPLITC * 768 + 255) & ~(size_t)255;
    unsigned* records = (unsigned*)(ws + off);             // B*CAPM words
    const size_t need = off + 4ull * B * CAPM + 4096;

    if (ws_size >= need) {
        hipMemsetAsync(gtotal, 0, 4ull * B, stream);
        k_pre<<<nbin + NBX, 512, 0, stream>>>(x, W1, part4, ei, gtotal, records,
                                              E, B, CH, nbin, N);
        k_deg<<<B, 256, 0, stream>>>(records, gtotal, part4, g4, N);
        k_msg2<<<B * SPLITC, 256, 0, stream>>>(records, gtotal, g4, psum);
        k_fin<<<(N + 255) / 256, 256, 0, stream>>>(psum, g4, b1, W2, b2, out, N);
    } else {
        // fallback: deg (N) + u4 (4N) in the part4 region, zeroed in k_xw1_fb
        float* deg = (float*)part4;
        float* u4  = deg + N;
        k_xw1_fb<<<4096, 256, 0, stream>>>(x, W1, g4, (unsigned*)deg, 5 * N, N);
        k_deg_fb<<<(E + 255) / 256, 256, 0, stream>>>(ei, deg, E);
        k_dinv_fb<<<(N + 255) / 256, 256, 0, stream>>>(deg, g4, N);
        k_edge_fb<<<(E + 255) / 256, 256, 0, stream>>>(ei, g4, u4, E);
        k_final_fb<<<(N + 255) / 256, 256, 0, stream>>>(u4, g4, b1, W2, b2, out, N);
    }
}

// Round 13
// 126.945 us; speedup vs baseline: 1.0747x; 1.0747x over previous
//
#include <hip/hip_runtime.h>
#include <stdint.h>

// GCN: h = relu( D^-1/2 (A+I) D^-1/2 (x@W1) + b1 ); z = h@W2 + b2
// out = [h (N*3) | z (N*7)] float32.
//
// Round-13: ATTRIBUTION round. Rounds 5-12 tuned a fused k_pre (bin+xw1)
// whose per-role cost was never measured; bin-containing kernels sat at
// 73-90us across every bin geometry. Unfuse into k_xw1 + k_bin with the
// best-known variant of each; consumers unchanged (R12 merged k_deg, R10
// uniform-loop k_msg2).
//   k_xw1 : x@W1 feature-split (wave = 4 nodes x 64-feat chunk) -> part4
//   k_bin : count -> atomic-reserve -> scatter, nbin=256 (R11's bin role)
//   k_deg : per-bucket degree histogram + g4 = {h*dinv, dinv} (merged)
//   k_msg2: message accumulate over valid range (SPLIT=8, 4-ILP loop) -> psum
//   k_fin : reduce + fused epilogue
// Norm factored: agg[d] = dinv[d]*( sum_{s->d} h[s]dinv[s] + h[d]dinv[d] ).

#define BSHIFT 8
#define BNODES 256
#define BPAD 392      // padded per-block bucket arrays
#define CAPM 16384    // record slots per bucket (mean 8184, sigma 90 -> +91s)
#define SPLITC 8      // msg2 slices per bucket

// block-wide int64-vs-int32 ballot: int64 LE => odd 32-bit words of first 256
// entries are all zero (ids < 2^17). Call from ALL threads before divergence.
__device__ __forceinline__ bool ei_is64(const unsigned* __restrict__ ei) {
    const int t = threadIdx.x;
    const int nz = (t < 256) && (ei[2 * t + 1] != 0u);
    return __syncthreads_or(nz) == 0;
}

// ---------- x@W1, feature-split: wave = 4 nodes, f = wave&3 (64 feats) ------
__global__ __launch_bounds__(512) void k_xw1(const float* __restrict__ x,
                                             const float* __restrict__ W1,
                                             float4* __restrict__ part4, int N) {
    const int gtid   = blockIdx.x * 512 + threadIdx.x;
    const int wave   = gtid >> 6;
    const int nwaves = (gridDim.x * 512) >> 6;
    const int lane   = threadIdx.x & 63;
    const int fg     = lane & 15;   // feature group within chunk
    const int m      = lane >> 4;   // node sub-index (0..3)
    const int f      = wave & 3;    // feature chunk
    const int wq     = wave >> 2;
    const int wstep  = nwaves >> 2;

    float w[4][3];
#pragma unroll
    for (int j = 0; j < 4; ++j)
#pragma unroll
        for (int c = 0; c < 3; ++c)
            w[j][c] = W1[(f * 64 + fg * 4 + j) * 3 + c];

    const int nq = (N + 3) >> 2;
    for (int q = wq; q < nq; q += 4 * wstep) {
        int nd[4]; bool ok[4]; float4 v[4];
#pragma unroll
        for (int u = 0; u < 4; ++u) {
            const int qu = q + u * wstep;
            nd[u] = qu * 4 + m;
            ok[u] = (qu < nq) && (nd[u] < N);
            v[u]  = ok[u] ? *reinterpret_cast<const float4*>(
                                x + (size_t)nd[u] * 256 + f * 64 + fg * 4)
                          : make_float4(0.f, 0.f, 0.f, 0.f);
        }
#pragma unroll
        for (int u = 0; u < 4; ++u) {
            float s0 = v[u].x * w[0][0] + v[u].y * w[1][0] + v[u].z * w[2][0] + v[u].w * w[3][0];
            float s1 = v[u].x * w[0][1] + v[u].y * w[1][1] + v[u].z * w[2][1] + v[u].w * w[3][1];
            float s2 = v[u].x * w[0][2] + v[u].y * w[1][2] + v[u].z * w[2][2] + v[u].w * w[3][2];
#pragma unroll
            for (int off = 8; off >= 1; off >>= 1) {
                s0 += __shfl_xor(s0, off, 64);
                s1 += __shfl_xor(s1, off, 64);
                s2 += __shfl_xor(s2, off, 64);
            }
            if (ok[u] && fg == 0)
                part4[(size_t)f * N + nd[u]] = make_float4(s0, s1, s2, 0.f);
        }
    }
}

// ---------- bin: count -> atomic-reserve -> scatter (CSR-lite) ----------
__global__ __launch_bounds__(512) void k_bin(const unsigned* __restrict__ ei,
                                             unsigned* __restrict__ gtotal,
                                             unsigned* __restrict__ records,
                                             int E, int B, int CH) {
    const bool is64 = ei_is64(ei);
    __shared__ unsigned cnt[BPAD], cur[BPAD];
    for (int i = threadIdx.x; i < BPAD; i += 512) cnt[i] = 0u;
    __syncthreads();
    const int e0 = blockIdx.x * CH;
    const int e1 = min(E, e0 + CH);
    // ---- phase 1: LDS histogram of dst buckets ----
    if (is64) {
        const uint4* dp = (const uint4*)(ei + 2 * (size_t)E + 2 * e0);
        const int n2 = (e1 - e0) >> 1;  // uint4 = 2 edges (lo words at .x/.z)
        for (int q = threadIdx.x; q < n2; q += 512) {
            const uint4 v = dp[q];
            atomicAdd(&cnt[v.x >> BSHIFT], 1u);
            atomicAdd(&cnt[v.z >> BSHIFT], 1u);
        }
        for (int e = e0 + 2 * n2 + threadIdx.x; e < e1; e += 512)
            atomicAdd(&cnt[ei[2 * (size_t)E + 2 * e] >> BSHIFT], 1u);
    } else {
        const uint4* dp = (const uint4*)(ei + (size_t)E + e0);
        const int n4 = (e1 - e0) >> 2;
        for (int q = threadIdx.x; q < n4; q += 512) {
            const uint4 v = dp[q];
            atomicAdd(&cnt[v.x >> BSHIFT], 1u);
            atomicAdd(&cnt[v.y >> BSHIFT], 1u);
            atomicAdd(&cnt[v.z >> BSHIFT], 1u);
            atomicAdd(&cnt[v.w >> BSHIFT], 1u);
        }
        for (int e = e0 + 4 * n4 + threadIdx.x; e < e1; e += 512)
            atomicAdd(&cnt[ei[(size_t)E + e] >> BSHIFT], 1u);
    }
    __syncthreads();
    // ---- phase 2: atomic reserve (order-free disjoint dense runs) ----
    for (int i = threadIdx.x; i < B; i += 512)
        cur[i] = cnt[i] ? atomicAdd(&gtotal[i], cnt[i]) : 0u;
    __syncthreads();
    // ---- phase 3: scatter (chunk re-read is L2/L3-hot) ----
    auto emit = [&](unsigned s, unsigned d) {
        const unsigned bb  = d >> BSHIFT;
        const unsigned pos = atomicAdd(&cur[bb], 1u);
        if (pos < (unsigned)CAPM)  // safety clamp; never hit at +91 sigma
            records[(size_t)bb * CAPM + pos] = (s << BSHIFT) | (d & (BNODES - 1));
    };
    const int nq = (e1 - e0) >> 2;
    if (is64) {
        const unsigned long long* e64 = (const unsigned long long*)ei;
        const ulonglong2* sp = (const ulonglong2*)(e64 + e0);
        const ulonglong2* dp = (const ulonglong2*)(e64 + (size_t)E + e0);
        for (int q = threadIdx.x; q < nq; q += 512) {
            const ulonglong2 sa = sp[2 * q], sb = sp[2 * q + 1];
            const ulonglong2 da = dp[2 * q], db = dp[2 * q + 1];
            emit((unsigned)sa.x, (unsigned)da.x);
            emit((unsigned)sa.y, (unsigned)da.y);
            emit((unsigned)sb.x, (unsigned)db.x);
            emit((unsigned)sb.y, (unsigned)db.y);
        }
        for (int e = e0 + 4 * nq + threadIdx.x; e < e1; e += 512)
            emit((unsigned)e64[e], (unsigned)e64[(size_t)E + e]);
    } else {
        const uint4* sp = (const uint4*)(ei + e0);
        const uint4* dp = (const uint4*)(ei + (size_t)E + e0);
        for (int q = threadIdx.x; q < nq; q += 512) {
            const uint4 s4 = sp[q], d4 = dp[q];
            emit(s4.x, d4.x);
            emit(s4.y, d4.y);
            emit(s4.z, d4.z);
            emit(s4.w, d4.w);
        }
        for (int e = e0 + 4 * nq + threadIdx.x; e < e1; e += 512)
            emit(ei[e], ei[(size_t)E + e]);
    }
}

// ---------- merged: per-bucket degree histogram + g4 = {h*dinv, dinv} --------
__global__ __launch_bounds__(256) void k_deg(const unsigned* __restrict__ records,
                                             const unsigned* __restrict__ gtotal,
                                             const float4* __restrict__ part4,
                                             float* __restrict__ g4, int N) {
    __shared__ unsigned cnt[BNODES];
    const int b = blockIdx.x;
    cnt[threadIdx.x] = 0u;
    __syncthreads();
    int n = (int)gtotal[b]; if (n > CAPM) n = CAPM;
    const unsigned* rec = records + (size_t)b * CAPM;
    for (int i = threadIdx.x; i < n; i += 1024) {  // 4-deep ILP, guarded
        const bool v1 = (i + 256) < n, v2 = (i + 512) < n, v3 = (i + 768) < n;
        const unsigned r0 = rec[i];
        const unsigned r1 = v1 ? rec[i + 256] : 0u;
        const unsigned r2 = v2 ? rec[i + 512] : 0u;
        const unsigned r3 = v3 ? rec[i + 768] : 0u;
        atomicAdd(&cnt[r0 & (BNODES - 1)], 1u);
        if (v1) atomicAdd(&cnt[r1 & (BNODES - 1)], 1u);
        if (v2) atomicAdd(&cnt[r2 & (BNODES - 1)], 1u);
        if (v3) atomicAdd(&cnt[r3 & (BNODES - 1)], 1u);
    }
    __syncthreads();
    const int node = (b << BSHIFT) + threadIdx.x;
    if (node < N) {
        const float4 p0 = part4[node];
        const float4 p1 = part4[(size_t)N + node];
        const float4 p2 = part4[(size_t)2 * N + node];
        const float4 p3 = part4[(size_t)3 * N + node];
        const float hx = p0.x + p1.x + p2.x + p3.x;
        const float hy = p0.y + p1.y + p2.y + p3.y;
        const float hz = p0.z + p1.z + p2.z + p3.z;
        const float r = rsqrtf(1.0f + (float)cnt[threadIdx.x]);  // +1 self-loop
        reinterpret_cast<float4*>(g4)[node] = make_float4(hx * r, hy * r, hz * r, r);
    }
}

// ---------- message accumulate: uniform-bound 4-ILP loop, SPLIT=8 ----------
__global__ __launch_bounds__(256) void k_msg2(const unsigned* __restrict__ records,
                                              const unsigned* __restrict__ total,
                                              const float* __restrict__ g4,
                                              float* __restrict__ psum) {
    __shared__ float acc[BNODES * 3];
    const int b  = blockIdx.x >> 3;
    const int sl = blockIdx.x & 7;
    for (int i = threadIdx.x; i < BNODES * 3; i += 256) acc[i] = 0.f;
    __syncthreads();
    int n = (int)total[b]; if (n > CAPM) n = CAPM;
    const int chunk = (n + SPLITC - 1) / SPLITC;
    const int lo = sl * chunk;
    const int hi = min(n, lo + chunk);
    const unsigned* rec = records + (size_t)b * CAPM;
    const float4* g4v = reinterpret_cast<const float4*>(g4);
    for (int i = lo + threadIdx.x; i < hi; i += 1024) {  // 4 gathers in flight
        const bool v1 = (i + 256) < hi, v2 = (i + 512) < hi, v3 = (i + 768) < hi;
        const unsigned r0 = rec[i];
        const unsigned r1 = v1 ? rec[i + 256] : 0u;
        const unsigned r2 = v2 ? rec[i + 512] : 0u;
        const unsigned r3 = v3 ? rec[i + 768] : 0u;
        const float4 g0 = g4v[r0 >> BSHIFT];
        const float4 g1 = g4v[r1 >> BSHIFT];
        const float4 g2 = g4v[r2 >> BSHIFT];
        const float4 g3 = g4v[r3 >> BSHIFT];
        const unsigned l0 = (r0 & (BNODES - 1)) * 3;
        atomicAdd(&acc[l0 + 0], g0.x); atomicAdd(&acc[l0 + 1], g0.y); atomicAdd(&acc[l0 + 2], g0.z);
        if (v1) {
            const unsigned l1 = (r1 & (BNODES - 1)) * 3;
            atomicAdd(&acc[l1 + 0], g1.x); atomicAdd(&acc[l1 + 1], g1.y); atomicAdd(&acc[l1 + 2], g1.z);
        }
        if (v2) {
            const unsigned l2 = (r2 & (BNODES - 1)) * 3;
            atomicAdd(&acc[l2 + 0], g2.x); atomicAdd(&acc[l2 + 1], g2.y); atomicAdd(&acc[l2 + 2], g2.z);
        }
        if (v3) {
            const unsigned l3 = (r3 & (BNODES - 1)) * 3;
            atomicAdd(&acc[l3 + 0], g3.x); atomicAdd(&acc[l3 + 1], g3.y); atomicAdd(&acc[l3 + 2], g3.z);
        }
    }
    __syncthreads();
    const size_t base = ((size_t)blockIdx.x * 3) << BSHIFT;  // [slice][c][256]
    psum[base +   0 + threadIdx.x] = acc[threadIdx.x * 3 + 0];
    psum[base + 256 + threadIdx.x] = acc[threadIdx.x * 3 + 1];
    psum[base + 512 + threadIdx.x] = acc[threadIdx.x * 3 + 2];
}

// ---------- reduce msg partials + fused epilogue ----------
__global__ __launch_bounds__(256) void k_fin(const float* __restrict__ psum,
                                             const float* __restrict__ g4,
                                             const float* __restrict__ b1,
                                             const float* __restrict__ W2,
                                             const float* __restrict__ b2,
                                             float* __restrict__ out, int N) {
    const int i = blockIdx.x * 256 + threadIdx.x;
    if (i >= N) return;
    const int b = i >> BSHIFT, t = i & (BNODES - 1);
    float a0 = 0.f, a1 = 0.f, a2 = 0.f;
#pragma unroll
    for (int s = 0; s < SPLITC; ++s) {
        const size_t base = (((size_t)b * SPLITC + s) * 3) << BSHIFT;
        a0 += psum[base + t];
        a1 += psum[base + 256 + t];
        a2 += psum[base + 512 + t];
    }
    const float4 g = reinterpret_cast<const float4*>(g4)[i];
    const float  r = g.w;
    const float h0 = fmaxf(r * (a0 + g.x) + b1[0], 0.f);
    const float h1 = fmaxf(r * (a1 + g.y) + b1[1], 0.f);
    const float h2 = fmaxf(r * (a2 + g.z) + b1[2], 0.f);
    out[3 * (size_t)i + 0] = h0;
    out[3 * (size_t)i + 1] = h1;
    out[3 * (size_t)i + 2] = h2;
    float* z = out + (size_t)3 * N;
#pragma unroll
    for (int c = 0; c < 7; ++c)
        z[7 * (size_t)i + c] = h0 * W2[c] + h1 * W2[7 + c] + h2 * W2[14 + c] + b2[c];
}

// ================= fallback (atomic path; only if ws too small) =============
__global__ __launch_bounds__(256) void k_xw1_fb(const float* __restrict__ x,
                                                const float* __restrict__ W1,
                                                float* __restrict__ g4,
                                                unsigned* __restrict__ zptr,
                                                int nzero, int N) {
    const int gtid = blockIdx.x * 256 + threadIdx.x;
    const int nthread = gridDim.x * 256;
    for (int i = gtid; i < nzero; i += nthread) zptr[i] = 0u;
    const int lane = threadIdx.x & 63;
    float w[4][3];
#pragma unroll
    for (int k = 0; k < 4; ++k)
#pragma unroll
        for (int c = 0; c < 3; ++c) w[k][c] = W1[(lane * 4 + k) * 3 + c];
    const int wave = gtid >> 6, nwaves = nthread >> 6;
    for (int node = wave; node < N; node += nwaves) {
        const float4 v = *reinterpret_cast<const float4*>(x + (size_t)node * 256 + lane * 4);
        float s0 = v.x * w[0][0] + v.y * w[1][0] + v.z * w[2][0] + v.w * w[3][0];
        float s1 = v.x * w[0][1] + v.y * w[1][1] + v.z * w[2][1] + v.w * w[3][1];
        float s2 = v.x * w[0][2] + v.y * w[1][2] + v.z * w[2][2] + v.w * w[3][2];
#pragma unroll
        for (int off = 32; off > 0; off >>= 1) {
            s0 += __shfl_xor(s0, off, 64);
            s1 += __shfl_xor(s1, off, 64);
            s2 += __shfl_xor(s2, off, 64);
        }
        if (lane == 0)
            reinterpret_cast<float4*>(g4)[node] = make_float4(s0, s1, s2, 0.f);
    }
}
__global__ __launch_bounds__(256) void k_deg_fb(const unsigned* __restrict__ ei,
                                                float* __restrict__ deg, int E) {
    const bool is64 = ei_is64(ei);
    const int e = blockIdx.x * 256 + threadIdx.x;
    if (e >= E) return;
    const unsigned d = is64 ? (unsigned)((const unsigned long long*)ei)[(size_t)E + e]
                            : ei[(size_t)E + e];
    atomicAdd(&deg[d], 1.0f);
}
__global__ __launch_bounds__(256) void k_dinv_fb(const float* __restrict__ deg,
                                                 float* __restrict__ g4, int N) {
    const int i = blockIdx.x * 256 + threadIdx.x;
    if (i >= N) return;
    const float r = rsqrtf(1.0f + deg[i]);
    const float4 h = reinterpret_cast<const float4*>(g4)[i];
    reinterpret_cast<float4*>(g4)[i] = make_float4(h.x * r, h.y * r, h.z * r, r);
}
__global__ __launch_bounds__(256) void k_edge_fb(const unsigned* __restrict__ ei,
                                                 const float* __restrict__ g4,
                                                 float* __restrict__ u4, int E) {
    const bool is64 = ei_is64(ei);
    const int e = blockIdx.x * 256 + threadIdx.x;
    if (e >= E) return;
    unsigned s, d;
    if (is64) {
        const unsigned long long* q = (const unsigned long long*)ei;
        s = (unsigned)q[e]; d = (unsigned)q[(size_t)E + e];
    } else {
        s = ei[e]; d = ei[(size_t)E + e];
    }
    const float4 g = reinterpret_cast<const float4*>(g4)[s];
    atomicAdd(&u4[4 * (size_t)d + 0], g.x);
    atomicAdd(&u4[4 * (size_t)d + 1], g.y);
    atomicAdd(&u4[4 * (size_t)d + 2], g.z);
}
__global__ __launch_bounds__(256) void k_final_fb(const float* __restrict__ u4,
                                                  const float* __restrict__ g4,
                                                  const float* __restrict__ b1,
                                                  const float* __restrict__ W2,
                                                  const float* __restrict__ b2,
                                                  float* __restrict__ out, int N) {
    const int i = blockIdx.x * 256 + threadIdx.x;
    if (i >= N) return;
    const float4 g = reinterpret_cast<const float4*>(g4)[i];
    const float4 u = reinterpret_cast<const float4*>(u4)[i];
    const float  r = g.w;
    const float h0 = fmaxf(r * (u.x + g.x) + b1[0], 0.f);
    const float h1 = fmaxf(r * (u.y + g.y) + b1[1], 0.f);
    const float h2 = fmaxf(r * (u.z + g.z) + b1[2], 0.f);
    out[3 * (size_t)i + 0] = h0;
    out[3 * (size_t)i + 1] = h1;
    out[3 * (size_t)i + 2] = h2;
    float* z = out + (size_t)3 * N;
#pragma unroll
    for (int c = 0; c < 7; ++c)
        z[7 * (size_t)i + c] = h0 * W2[c] + h1 * W2[7 + c] + h2 * W2[14 + c] + b2[c];
}

extern "C" void kernel_launch(void* const* d_in, const int* in_sizes, int n_in,
                              void* d_out, int out_size, void* d_ws, size_t ws_size,
                              hipStream_t stream) {
    const float*    x   = (const float*)d_in[0];
    const unsigned* ei  = (const unsigned*)d_in[1];
    const float*    W1  = (const float*)d_in[2];
    const float*    b1  = (const float*)d_in[3];
    const float*    W2  = (const float*)d_in[4];
    const float*    b2  = (const float*)d_in[5];
    float*          out = (float*)d_out;

    const int N = in_sizes[0] / 256;          // 100000
    const int E = in_sizes[1] / 2;            // 3200000
    const int B = (N + BNODES - 1) >> BSHIFT; // 391

    // bin geometry: ~256 blocks (R11's best), chunk multiple of 4
    const int CH   = ((E + 255) / 256 + 3) & ~3;
    const int nbin = (E + CH - 1) / CH;       // <= 256

    // ---- workspace layout ----
    char* ws = (char*)d_ws;
    size_t off = 256;
    float*    g4      = (float*)(ws + off);                // 4N {h*dinv, dinv}
    off = (off + 16ull * N + 255) & ~(size_t)255;
    float4*   part4   = (float4*)(ws + off);               // 4 x N xw1 partials
    off = (off + 64ull * N + 255) & ~(size_t)255;
    unsigned* gtotal  = (unsigned*)(ws + off);             // B (memset to 0)
    off = (off + 4ull * B + 255) & ~(size_t)255;
    float*    psum    = (float*)(ws + off);                // B*SPLITC*768 f32
    off = (off + 4ull * B * SPLITC * 768 + 255) & ~(size_t)255;
    unsigned* records = (unsigned*)(ws + off);             // B*CAPM words
    const size_t need = off + 4ull * B * CAPM + 4096;

    if (ws_size >= need) {
        hipMemsetAsync(gtotal, 0, 4ull * B, stream);
        k_xw1<<<1024, 512, 0, stream>>>(x, W1, part4, N);
        k_bin<<<nbin, 512, 0, stream>>>(ei, gtotal, records, E, B, CH);
        k_deg<<<B, 256, 0, stream>>>(records, gtotal, part4, g4, N);
        k_msg2<<<B * SPLITC, 256, 0, stream>>>(records, gtotal, g4, psum);
        k_fin<<<(N + 255) / 256, 256, 0, stream>>>(psum, g4, b1, W2, b2, out, N);
    } else {
        // fallback: deg (N) + u4 (4N) in the part4 region, zeroed in k_xw1_fb
        float* deg = (float*)part4;
        float* u4  = deg + N;
        k_xw1_fb<<<4096, 256, 0, stream>>>(x, W1, g4, (unsigned*)deg, 5 * N, N);
        k_deg_fb<<<(E + 255) / 256, 256, 0, stream>>>(ei, deg, E);
        k_dinv_fb<<<(N + 255) / 256, 256, 0, stream>>>(deg, g4, N);
        k_edge_fb<<<(E + 255) / 256, 256, 0, stream>>>(ei, g4, u4, E);
        k_final_fb<<<(N + 255) / 256, 256, 0, stream>>>(u4, g4, b1, W2, b2, out, N);
    }
}

// Round 14
// 116.524 us; speedup vs baseline: 1.1708x; 1.0894x over previous
//
#include <hip/hip_runtime.h>
#include <stdint.h>

// GCN: h = relu( D^-1/2 (A+I) D^-1/2 (x@W1) + b1 ); z = h@W2 + b2
// out = [h (N*3) | z (N*7)] float32.
//
// Round-14: R12/R13's consumer regression isolated — the 4-ILP loops with
// per-slot GUARDED loads (`v1 ? rec[i+256] : 0`) serialize the gathers just
// like R9's predicated slots (msg2 = 58us). Revert consumers to R10's proven
// 2-ILP UNGUARDED uniform-bound loop (no per-record branch; tail after loop).
// Keep: unfused k_xw1/k_bin (serial pair measured cheaper than R11's fused
// 80us), CSR-lite atomic-reserve binning, merged k_deg, fused epilogue.
//   k_xw1 : x@W1 feature-split (wave = 4 nodes x 64-feat chunk) -> part4
//           + zeroes gtotal (block 0) so no memset node
//   k_bin : count -> atomic-reserve -> scatter, nbin=256
//   k_deg : per-bucket degree histogram (2-ILP) + g4 = {h*dinv, dinv}
//   k_msg2: message accumulate (SPLIT=8, 2-ILP unguarded) -> psum
//   k_fin : reduce + fused epilogue
// Norm factored: agg[d] = dinv[d]*( sum_{s->d} h[s]dinv[s] + h[d]dinv[d] ).

#define BSHIFT 8
#define BNODES 256
#define BPAD 392      // padded per-block bucket arrays
#define CAPM 16384    // record slots per bucket (mean 8184, sigma 90 -> +91s)
#define SPLITC 8      // msg2 slices per bucket

// block-wide int64-vs-int32 ballot: int64 LE => odd 32-bit words of first 256
// entries are all zero (ids < 2^17). Call from ALL threads before divergence.
__device__ __forceinline__ bool ei_is64(const unsigned* __restrict__ ei) {
    const int t = threadIdx.x;
    const int nz = (t < 256) && (ei[2 * t + 1] != 0u);
    return __syncthreads_or(nz) == 0;
}

// ---------- x@W1, feature-split: wave = 4 nodes, f = wave&3 (64 feats) ------
__global__ __launch_bounds__(512) void k_xw1(const float* __restrict__ x,
                                             const float* __restrict__ W1,
                                             float4* __restrict__ part4,
                                             unsigned* __restrict__ gtotal,
                                             int B, int N) {
    if (blockIdx.x == 0)  // zero the reserve counters (k_bin runs after us)
        for (int i = threadIdx.x; i < B; i += 512) gtotal[i] = 0u;

    const int gtid   = blockIdx.x * 512 + threadIdx.x;
    const int wave   = gtid >> 6;
    const int nwaves = (gridDim.x * 512) >> 6;
    const int lane   = threadIdx.x & 63;
    const int fg     = lane & 15;   // feature group within chunk
    const int m      = lane >> 4;   // node sub-index (0..3)
    const int f      = wave & 3;    // feature chunk
    const int wq     = wave >> 2;
    const int wstep  = nwaves >> 2;

    float w[4][3];
#pragma unroll
    for (int j = 0; j < 4; ++j)
#pragma unroll
        for (int c = 0; c < 3; ++c)
            w[j][c] = W1[(f * 64 + fg * 4 + j) * 3 + c];

    const int nq = (N + 3) >> 2;
    for (int q = wq; q < nq; q += 4 * wstep) {
        int nd[4]; bool ok[4]; float4 v[4];
#pragma unroll
        for (int u = 0; u < 4; ++u) {
            const int qu = q + u * wstep;
            nd[u] = qu * 4 + m;
            ok[u] = (qu < nq) && (nd[u] < N);
            v[u]  = ok[u] ? *reinterpret_cast<const float4*>(
                                x + (size_t)nd[u] * 256 + f * 64 + fg * 4)
                          : make_float4(0.f, 0.f, 0.f, 0.f);
        }
#pragma unroll
        for (int u = 0; u < 4; ++u) {
            float s0 = v[u].x * w[0][0] + v[u].y * w[1][0] + v[u].z * w[2][0] + v[u].w * w[3][0];
            float s1 = v[u].x * w[0][1] + v[u].y * w[1][1] + v[u].z * w[2][1] + v[u].w * w[3][1];
            float s2 = v[u].x * w[0][2] + v[u].y * w[1][2] + v[u].z * w[2][2] + v[u].w * w[3][2];
#pragma unroll
            for (int off = 8; off >= 1; off >>= 1) {
                s0 += __shfl_xor(s0, off, 64);
                s1 += __shfl_xor(s1, off, 64);
                s2 += __shfl_xor(s2, off, 64);
            }
            if (ok[u] && fg == 0)
                part4[(size_t)f * N + nd[u]] = make_float4(s0, s1, s2, 0.f);
        }
    }
}

// ---------- bin: count -> atomic-reserve -> scatter (CSR-lite) ----------
__global__ __launch_bounds__(512) void k_bin(const unsigned* __restrict__ ei,
                                             unsigned* __restrict__ gtotal,
                                             unsigned* __restrict__ records,
                                             int E, int B, int CH) {
    const bool is64 = ei_is64(ei);
    __shared__ unsigned cnt[BPAD], cur[BPAD];
    for (int i = threadIdx.x; i < BPAD; i += 512) cnt[i] = 0u;
    __syncthreads();
    const int e0 = blockIdx.x * CH;
    const int e1 = min(E, e0 + CH);
    // ---- phase 1: LDS histogram of dst buckets ----
    if (is64) {
        const uint4* dp = (const uint4*)(ei + 2 * (size_t)E + 2 * e0);
        const int n2 = (e1 - e0) >> 1;  // uint4 = 2 edges (lo words at .x/.z)
        for (int q = threadIdx.x; q < n2; q += 512) {
            const uint4 v = dp[q];
            atomicAdd(&cnt[v.x >> BSHIFT], 1u);
            atomicAdd(&cnt[v.z >> BSHIFT], 1u);
        }
        for (int e = e0 + 2 * n2 + threadIdx.x; e < e1; e += 512)
            atomicAdd(&cnt[ei[2 * (size_t)E + 2 * e] >> BSHIFT], 1u);
    } else {
        const uint4* dp = (const uint4*)(ei + (size_t)E + e0);
        const int n4 = (e1 - e0) >> 2;
        for (int q = threadIdx.x; q < n4; q += 512) {
            const uint4 v = dp[q];
            atomicAdd(&cnt[v.x >> BSHIFT], 1u);
            atomicAdd(&cnt[v.y >> BSHIFT], 1u);
            atomicAdd(&cnt[v.z >> BSHIFT], 1u);
            atomicAdd(&cnt[v.w >> BSHIFT], 1u);
        }
        for (int e = e0 + 4 * n4 + threadIdx.x; e < e1; e += 512)
            atomicAdd(&cnt[ei[(size_t)E + e] >> BSHIFT], 1u);
    }
    __syncthreads();
    // ---- phase 2: atomic reserve (order-free disjoint dense runs) ----
    for (int i = threadIdx.x; i < B; i += 512)
        cur[i] = cnt[i] ? atomicAdd(&gtotal[i], cnt[i]) : 0u;
    __syncthreads();
    // ---- phase 3: scatter (chunk re-read is L2/L3-hot) ----
    auto emit = [&](unsigned s, unsigned d) {
        const unsigned bb  = d >> BSHIFT;
        const unsigned pos = atomicAdd(&cur[bb], 1u);
        if (pos < (unsigned)CAPM)  // safety clamp; never hit at +91 sigma
            records[(size_t)bb * CAPM + pos] = (s << BSHIFT) | (d & (BNODES - 1));
    };
    const int nq = (e1 - e0) >> 2;
    if (is64) {
        const unsigned long long* e64 = (const unsigned long long*)ei;
        const ulonglong2* sp = (const ulonglong2*)(e64 + e0);
        const ulonglong2* dp = (const ulonglong2*)(e64 + (size_t)E + e0);
        for (int q = threadIdx.x; q < nq; q += 512) {
            const ulonglong2 sa = sp[2 * q], sb = sp[2 * q + 1];
            const ulonglong2 da = dp[2 * q], db = dp[2 * q + 1];
            emit((unsigned)sa.x, (unsigned)da.x);
            emit((unsigned)sa.y, (unsigned)da.y);
            emit((unsigned)sb.x, (unsigned)db.x);
            emit((unsigned)sb.y, (unsigned)db.y);
        }
        for (int e = e0 + 4 * nq + threadIdx.x; e < e1; e += 512)
            emit((unsigned)e64[e], (unsigned)e64[(size_t)E + e]);
    } else {
        const uint4* sp = (const uint4*)(ei + e0);
        const uint4* dp = (const uint4*)(ei + (size_t)E + e0);
        for (int q = threadIdx.x; q < nq; q += 512) {
            const uint4 s4 = sp[q], d4 = dp[q];
            emit(s4.x, d4.x);
            emit(s4.y, d4.y);
            emit(s4.z, d4.z);
            emit(s4.w, d4.w);
        }
        for (int e = e0 + 4 * nq + threadIdx.x; e < e1; e += 512)
            emit(ei[e], ei[(size_t)E + e]);
    }
}

// ---------- merged: per-bucket degree histogram (2-ILP) + g4 scale ----------
__global__ __launch_bounds__(256) void k_deg(const unsigned* __restrict__ records,
                                             const unsigned* __restrict__ gtotal,
                                             const float4* __restrict__ part4,
                                             float* __restrict__ g4, int N) {
    __shared__ unsigned cnt[BNODES];
    const int b = blockIdx.x;
    cnt[threadIdx.x] = 0u;
    __syncthreads();
    int n = (int)gtotal[b]; if (n > CAPM) n = CAPM;
    const unsigned* rec = records + (size_t)b * CAPM;
    int i = threadIdx.x;
    for (; i + 256 < n; i += 512) {  // 2-ILP, no per-record divergence
        const unsigned r0 = rec[i], r1 = rec[i + 256];
        atomicAdd(&cnt[r0 & (BNODES - 1)], 1u);
        atomicAdd(&cnt[r1 & (BNODES - 1)], 1u);
    }
    if (i < n) atomicAdd(&cnt[rec[i] & (BNODES - 1)], 1u);
    __syncthreads();
    const int node = (b << BSHIFT) + threadIdx.x;
    if (node < N) {
        const float4 p0 = part4[node];
        const float4 p1 = part4[(size_t)N + node];
        const float4 p2 = part4[(size_t)2 * N + node];
        const float4 p3 = part4[(size_t)3 * N + node];
        const float hx = p0.x + p1.x + p2.x + p3.x;
        const float hy = p0.y + p1.y + p2.y + p3.y;
        const float hz = p0.z + p1.z + p2.z + p3.z;
        const float r = rsqrtf(1.0f + (float)cnt[threadIdx.x]);  // +1 self-loop
        reinterpret_cast<float4*>(g4)[node] = make_float4(hx * r, hy * r, hz * r, r);
    }
}

// ---------- message accumulate: uniform-bound 2-ILP loop, SPLIT=8 ----------
__global__ __launch_bounds__(256) void k_msg2(const unsigned* __restrict__ records,
                                              const unsigned* __restrict__ total,
                                              const float* __restrict__ g4,
                                              float* __restrict__ psum) {
    __shared__ float acc[BNODES * 3];
    const int b  = blockIdx.x >> 3;
    const int sl = blockIdx.x & 7;
    for (int i = threadIdx.x; i < BNODES * 3; i += 256) acc[i] = 0.f;
    __syncthreads();
    int n = (int)total[b]; if (n > CAPM) n = CAPM;
    const int chunk = (n + SPLITC - 1) / SPLITC;
    const int lo = sl * chunk;
    const int hi = min(n, lo + chunk);
    const unsigned* rec = records + (size_t)b * CAPM;
    const float4* g4v = reinterpret_cast<const float4*>(g4);
    int i = lo + threadIdx.x;
    for (; i + 256 < hi; i += 512) {  // 2 independent gathers in flight
        const unsigned r0 = rec[i], r1 = rec[i + 256];
        const float4 ga = g4v[r0 >> BSHIFT];
        const float4 gb = g4v[r1 >> BSHIFT];
        const unsigned l0 = (r0 & (BNODES - 1)) * 3, l1 = (r1 & (BNODES - 1)) * 3;
        atomicAdd(&acc[l0 + 0], ga.x); atomicAdd(&acc[l0 + 1], ga.y); atomicAdd(&acc[l0 + 2], ga.z);
        atomicAdd(&acc[l1 + 0], gb.x); atomicAdd(&acc[l1 + 1], gb.y); atomicAdd(&acc[l1 + 2], gb.z);
    }
    if (i < hi) {
        const unsigned r0 = rec[i];
        const float4 ga = g4v[r0 >> BSHIFT];
        const unsigned l0 = (r0 & (BNODES - 1)) * 3;
        atomicAdd(&acc[l0 + 0], ga.x); atomicAdd(&acc[l0 + 1], ga.y); atomicAdd(&acc[l0 + 2], ga.z);
    }
    __syncthreads();
    const size_t base = ((size_t)blockIdx.x * 3) << BSHIFT;  // [slice][c][256]
    psum[base +   0 + threadIdx.x] = acc[threadIdx.x * 3 + 0];
    psum[base + 256 + threadIdx.x] = acc[threadIdx.x * 3 + 1];
    psum[base + 512 + threadIdx.x] = acc[threadIdx.x * 3 + 2];
}

// ---------- reduce msg partials + fused epilogue ----------
__global__ __launch_bounds__(256) void k_fin(const float* __restrict__ psum,
                                             const float* __restrict__ g4,
                                             const float* __restrict__ b1,
                                             const float* __restrict__ W2,
                                             const float* __restrict__ b2,
                                             float* __restrict__ out, int N) {
    const int i = blockIdx.x * 256 + threadIdx.x;
    if (i >= N) return;
    const int b = i >> BSHIFT, t = i & (BNODES - 1);
    float a0 = 0.f, a1 = 0.f, a2 = 0.f;
#pragma unroll
    for (int s = 0; s < SPLITC; ++s) {
        const size_t base = (((size_t)b * SPLITC + s) * 3) << BSHIFT;
        a0 += psum[base + t];
        a1 += psum[base + 256 + t];
        a2 += psum[base + 512 + t];
    }
    const float4 g = reinterpret_cast<const float4*>(g4)[i];
    const float  r = g.w;
    const float h0 = fmaxf(r * (a0 + g.x) + b1[0], 0.f);
    const float h1 = fmaxf(r * (a1 + g.y) + b1[1], 0.f);
    const float h2 = fmaxf(r * (a2 + g.z) + b1[2], 0.f);
    out[3 * (size_t)i + 0] = h0;
    out[3 * (size_t)i + 1] = h1;
    out[3 * (size_t)i + 2] = h2;
    float* z = out + (size_t)3 * N;
#pragma unroll
    for (int c = 0; c < 7; ++c)
        z[7 * (size_t)i + c] = h0 * W2[c] + h1 * W2[7 + c] + h2 * W2[14 + c] + b2[c];
}

// ================= fallback (atomic path; only if ws too small) =============
__global__ __launch_bounds__(256) void k_xw1_fb(const float* __restrict__ x,
                                                const float* __restrict__ W1,
                                                float* __restrict__ g4,
                                                unsigned* __restrict__ zptr,
                                                int nzero, int N) {
    const int gtid = blockIdx.x * 256 + threadIdx.x;
    const int nthread = gridDim.x * 256;
    for (int i = gtid; i < nzero; i += nthread) zptr[i] = 0u;
    const int lane = threadIdx.x & 63;
    float w[4][3];
#pragma unroll
    for (int k = 0; k < 4; ++k)
#pragma unroll
        for (int c = 0; c < 3; ++c) w[k][c] = W1[(lane * 4 + k) * 3 + c];
    const int wave = gtid >> 6, nwaves = nthread >> 6;
    for (int node = wave; node < N; node += nwaves) {
        const float4 v = *reinterpret_cast<const float4*>(x + (size_t)node * 256 + lane * 4);
        float s0 = v.x * w[0][0] + v.y * w[1][0] + v.z * w[2][0] + v.w * w[3][0];
        float s1 = v.x * w[0][1] + v.y * w[1][1] + v.z * w[2][1] + v.w * w[3][1];
        float s2 = v.x * w[0][2] + v.y * w[1][2] + v.z * w[2][2] + v.w * w[3][2];
#pragma unroll
        for (int off = 32; off > 0; off >>= 1) {
            s0 += __shfl_xor(s0, off, 64);
            s1 += __shfl_xor(s1, off, 64);
            s2 += __shfl_xor(s2, off, 64);
        }
        if (lane == 0)
            reinterpret_cast<float4*>(g4)[node] = make_float4(s0, s1, s2, 0.f);
    }
}
__global__ __launch_bounds__(256) void k_deg_fb(const unsigned* __restrict__ ei,
                                                float* __restrict__ deg, int E) {
    const bool is64 = ei_is64(ei);
    const int e = blockIdx.x * 256 + threadIdx.x;
    if (e >= E) return;
    const unsigned d = is64 ? (unsigned)((const unsigned long long*)ei)[(size_t)E + e]
                            : ei[(size_t)E + e];
    atomicAdd(&deg[d], 1.0f);
}
__global__ __launch_bounds__(256) void k_dinv_fb(const float* __restrict__ deg,
                                                 float* __restrict__ g4, int N) {
    const int i = blockIdx.x * 256 + threadIdx.x;
    if (i >= N) return;
    const float r = rsqrtf(1.0f + deg[i]);
    const float4 h = reinterpret_cast<const float4*>(g4)[i];
    reinterpret_cast<float4*>(g4)[i] = make_float4(h.x * r, h.y * r, h.z * r, r);
}
__global__ __launch_bounds__(256) void k_edge_fb(const unsigned* __restrict__ ei,
                                                 const float* __restrict__ g4,
                                                 float* __restrict__ u4, int E) {
    const bool is64 = ei_is64(ei);
    const int e = blockIdx.x * 256 + threadIdx.x;
    if (e >= E) return;
    unsigned s, d;
    if (is64) {
        const unsigned long long* q = (const unsigned long long*)ei;
        s = (unsigned)q[e]; d = (unsigned)q[(size_t)E + e];
    } else {
        s = ei[e]; d = ei[(size_t)E + e];
    }
    const float4 g = reinterpret_cast<const float4*>(g4)[s];
    atomicAdd(&u4[4 * (size_t)d + 0], g.x);
    atomicAdd(&u4[4 * (size_t)d + 1], g.y);
    atomicAdd(&u4[4 * (size_t)d + 2], g.z);
}
__global__ __launch_bounds__(256) void k_final_fb(const float* __restrict__ u4,
                                                  const float* __restrict__ g4,
                                                  const float* __restrict__ b1,
                                                  const float* __restrict__ W2,
                                                  const float* __restrict__ b2,
                                                  float* __restrict__ out, int N) {
    const int i = blockIdx.x * 256 + threadIdx.x;
    if (i >= N) return;
    const float4 g = reinterpret_cast<const float4*>(g4)[i];
    const float4 u = reinterpret_cast<const float4*>(u4)[i];
    const float  r = g.w;
    const float h0 = fmaxf(r * (u.x + g.x) + b1[0], 0.f);
    const float h1 = fmaxf(r * (u.y + g.y) + b1[1], 0.f);
    const float h2 = fmaxf(r * (u.z + g.z) + b1[2], 0.f);
    out[3 * (size_t)i + 0] = h0;
    out[3 * (size_t)i + 1] = h1;
    out[3 * (size_t)i + 2] = h2;
    float* z = out + (size_t)3 * N;
#pragma unroll
    for (int c = 0; c < 7; ++c)
        z[7 * (size_t)i + c] = h0 * W2[c] + h1 * W2[7 + c] + h2 * W2[14 + c] + b2[c];
}

extern "C" void kernel_launch(void* const* d_in, const int* in_sizes, int n_in,
                              void* d_out, int out_size, void* d_ws, size_t ws_size,
                              hipStream_t stream) {
    const float*    x   = (const float*)d_in[0];
    const unsigned* ei  = (const unsigned*)d_in[1];
    const float*    W1  = (const float*)d_in[2];
    const float*    b1  = (const float*)d_in[3];
    const float*    W2  = (const float*)d_in[4];
    const float*    b2  = (const float*)d_in[5];
    float*          out = (float*)d_out;

    const int N = in_sizes[0] / 256;          // 100000
    const int E = in_sizes[1] / 2;            // 3200000
    const int B = (N + BNODES - 1) >> BSHIFT; // 391

    // bin geometry: ~256 blocks, chunk multiple of 4
    const int CH   = ((E + 255) / 256 + 3) & ~3;
    const int nbin = (E + CH - 1) / CH;       // <= 256

    // ---- workspace layout ----
    char* ws = (char*)d_ws;
    size_t off = 256;
    float*    g4      = (float*)(ws + off);                // 4N {h*dinv, dinv}
    off = (off + 16ull * N + 255) & ~(size_t)255;
    float4*   part4   = (float4*)(ws + off);               // 4 x N xw1 partials
    off = (off + 64ull * N + 255) & ~(size_t)255;
    unsigned* gtotal  = (unsigned*)(ws + off);             // B (zeroed in k_xw1)
    off = (off + 4ull * B + 255) & ~(size_t)255;
    float*    psum    = (float*)(ws + off);                // B*SPLITC*768 f32
    off = (off + 4ull * B * SPLITC * 768 + 255) & ~(size_t)255;
    unsigned* records = (unsigned*)(ws + off);             // B*CAPM words
    const size_t need = off + 4ull * B * CAPM + 4096;

    if (ws_size >= need) {
        k_xw1<<<1024, 512, 0, stream>>>(x, W1, part4, gtotal, B, N);
        k_bin<<<nbin, 512, 0, stream>>>(ei, gtotal, records, E, B, CH);
        k_deg<<<B, 256, 0, stream>>>(records, gtotal, part4, g4, N);
        k_msg2<<<B * SPLITC, 256, 0, stream>>>(records, gtotal, g4, psum);
        k_fin<<<(N + 255) / 256, 256, 0, stream>>>(psum, g4, b1, W2, b2, out, N);
    } else {
        // fallback: deg (N) + u4 (4N) in the part4 region, zeroed in k_xw1_fb
        float* deg = (float*)part4;
        float* u4  = deg + N;
        k_xw1_fb<<<4096, 256, 0, stream>>>(x, W1, g4, (unsigned*)deg, 5 * N, N);
        k_deg_fb<<<(E + 255) / 256, 256, 0, stream>>>(ei, deg, E);
        k_dinv_fb<<<(N + 255) / 256, 256, 0, stream>>>(deg, g4, N);
        k_edge_fb<<<(E + 255) / 256, 256, 0, stream>>>(ei, g4, u4, E);
        k_final_fb<<<(N + 255) / 256, 256, 0, stream>>>(u4, g4, b1, W2, b2, out, N);
    }
}